// Round 4
// baseline (435.915 us; speedup 1.0000x reference)
//
#include <hip/hip_runtime.h>
#include <hip/hip_bf16.h>

#define N_NODES 100000
#define N_EDGES 800000
#define D 64
#define SCAN_B 256
#define NB1 ((N_NODES + SCAN_B - 1) / SCAN_B)   // 391 blocks
#define FILL_BLOCKS (N_EDGES / 256)             // 3125, exact
#define INIT_BLOCKS (N_NODES * D / 256)         // 25000, exact

// ---------------------------------------------------------------------------
// hist + rank: deg[dst]++, rank[e] = arrival order of edge e at its dst.
__global__ __launch_bounds__(256) void hist_rank_kernel(
        const int2* __restrict__ edges,
        int* __restrict__ deg,
        int* __restrict__ rank) {
    int t = blockIdx.x * 256 + threadIdx.x;
    int2 e = edges[t];                      // grid exact: 3125*256 == N_EDGES
    rank[t] = atomicAdd(&deg[e.y], 1);
}

// ---------------------------------------------------------------------------
// Scans (exclusive prefix over deg -> row_ptr)
__global__ void scan1_kernel(const int* __restrict__ deg,
                             int* __restrict__ row_ptr,
                             int* __restrict__ bsum) {
    __shared__ int tmp[SCAN_B];
    int t = threadIdx.x;
    int i = blockIdx.x * SCAN_B + t;
    int v = (i < N_NODES) ? deg[i] : 0;
    tmp[t] = v;
    __syncthreads();
#pragma unroll
    for (int off = 1; off < SCAN_B; off <<= 1) {
        int a = (t >= off) ? tmp[t - off] : 0;
        __syncthreads();
        tmp[t] += a;
        __syncthreads();
    }
    if (i < N_NODES) row_ptr[i] = tmp[t] - v;   // exclusive
    if (t == SCAN_B - 1) bsum[blockIdx.x] = tmp[t];
}

__global__ void scan2_kernel(const int* __restrict__ bsum, int* __restrict__ boff) {
    __shared__ int tmp[512];
    int t = threadIdx.x;
    int v = (t < NB1) ? bsum[t] : 0;
    tmp[t] = v;
    __syncthreads();
#pragma unroll
    for (int off = 1; off < 512; off <<= 1) {
        int a = (t >= off) ? tmp[t - off] : 0;
        __syncthreads();
        tmp[t] += a;
        __syncthreads();
    }
    if (t < NB1) boff[t] = tmp[t] - v;
}

__global__ void scan3_kernel(int* __restrict__ row_ptr,
                             const int* __restrict__ boff) {
    int i = blockIdx.x * SCAN_B + threadIdx.x;
    if (i < N_NODES) row_ptr[i] += boff[i >> 8];
    if (i == 0) row_ptr[N_NODES] = N_EDGES;
}

// ---------------------------------------------------------------------------
// Fused dispatch: blocks [0, FILL_BLOCKS) scatter CSR cols (atomic-free, uses
// rank); blocks [FILL_BLOCKS, +INIT_BLOCKS) compute initial embeddings.
__global__ __launch_bounds__(256) void fill_init_kernel(
        const int2* __restrict__ edges,
        const int* __restrict__ rank,
        const int* __restrict__ rowp,
        int* __restrict__ col,
        const int* __restrict__ nodes,
        const float* __restrict__ features,
        const float* __restrict__ node_emb,
        const float* __restrict__ feat_W,
        const float* __restrict__ feat_b,
        float* __restrict__ embeds) {
    if (blockIdx.x < FILL_BLOCKS) {
        int t = blockIdx.x * 256 + threadIdx.x;
        int2 e = edges[t];
        col[rowp[e.y] + rank[t]] = e.x;
    } else {
        int tid = (blockIdx.x - FILL_BLOCKS) * 256 + threadIdx.x;
        int node = tid >> 6;
        int d = tid & 63;
        float acc = feat_b[d];
        const float* f = features + (size_t)node * 10;
        const float* w = feat_W + (size_t)d * 10;
#pragma unroll
        for (int j = 0; j < 10; ++j) acc += f[j] * w[j];
        embeds[tid] = node_emb[(size_t)nodes[node] * D + d] + acc;
    }
}

// ---------------------------------------------------------------------------
// Fused gather + conv (+ optional cosine score).
// Gather: 16 groups x 16 lanes; group g owns node blockIdx*16+g; lane c holds
// float4 chunk c. Unroll-4: 4 independent row loads in flight per group.
// Conv: wave w computes nodes w*4..w*4+3; lane d = output dim; W row d in
// VGPRs (loaded AFTER gather -> short liveness, no spill across gather loop).
template <bool SCORE>
__global__ __launch_bounds__(256) void fused_gather_conv_kernel(
        const float* __restrict__ emb_in,
        const int* __restrict__ rowp,
        const int* __restrict__ col,
        const float* __restrict__ W,
        const float* __restrict__ b,
        const float* __restrict__ pattern_emb,
        const int* __restrict__ pattern_id,
        float* __restrict__ emb_out,
        float* __restrict__ score_out) {
    __shared__ float4 xs[16][16];            // 16 nodes x 64 floats = 4 KB

    int tid = threadIdx.x;
    int g = tid >> 4;                        // group 0..15
    int c = tid & 15;                        // float4 chunk
    int node0 = blockIdx.x * 16;             // grid = 6250, exact
    int node = node0 + g;

    int start = rowp[node];
    int end   = rowp[node + 1];

    float4 acc = ((const float4*)(emb_in + (size_t)node * D))[c];   // self term

    int e = start;
    for (; e + 4 <= end; e += 4) {
        int s0 = col[e], s1 = col[e + 1], s2 = col[e + 2], s3 = col[e + 3];
        float4 v0 = ((const float4*)(emb_in + (size_t)s0 * D))[c];
        float4 v1 = ((const float4*)(emb_in + (size_t)s1 * D))[c];
        float4 v2 = ((const float4*)(emb_in + (size_t)s2 * D))[c];
        float4 v3 = ((const float4*)(emb_in + (size_t)s3 * D))[c];
        acc.x += (v0.x + v1.x) + (v2.x + v3.x);
        acc.y += (v0.y + v1.y) + (v2.y + v3.y);
        acc.z += (v0.z + v1.z) + (v2.z + v3.z);
        acc.w += (v0.w + v1.w) + (v2.w + v3.w);
    }
    for (; e < end; ++e) {
        float4 v = ((const float4*)(emb_in + (size_t)col[e] * D))[c];
        acc.x += v.x; acc.y += v.y; acc.z += v.z; acc.w += v.w;
    }
    xs[g][c] = acc;
    __syncthreads();

    // ---- conv phase ----
    int lane = tid & 63;
    int wv   = tid >> 6;                     // 0..3
    float bias = b[lane];
    float4 Wr[16];
    const float4* W4 = (const float4*)(W + (size_t)lane * D);
#pragma unroll
    for (int k = 0; k < 16; ++k) Wr[k] = W4[k];

    float y[4];
#pragma unroll
    for (int j = 0; j < 4; ++j) {
        int n = wv * 4 + j;
        float a2 = bias;
#pragma unroll
        for (int k = 0; k < 16; ++k) {
            float4 x4 = xs[n][k];            // wave-broadcast ds_read_b128
            a2 += Wr[k].x * x4.x + Wr[k].y * x4.y + Wr[k].z * x4.z + Wr[k].w * x4.w;
        }
        y[j] = fmaxf(a2, 0.0f);
    }

    if (!SCORE) {
#pragma unroll
        for (int j = 0; j < 4; ++j)
            emb_out[(size_t)(node0 + wv * 4 + j) * D + lane] = y[j];
    } else {
        int pid = pattern_id[0];
        float p = pattern_emb[(size_t)pid * D + lane];
        float pn = p * p;
#pragma unroll
        for (int m = 32; m > 0; m >>= 1) pn += __shfl_xor(pn, m, 64);
        float pnorm = fmaxf(sqrtf(pn), 1e-8f);
#pragma unroll
        for (int j = 0; j < 4; ++j) {
            float dot = y[j] * p;
            float n2  = y[j] * y[j];
#pragma unroll
            for (int m = 32; m > 0; m >>= 1) {
                dot += __shfl_xor(dot, m, 64);
                n2  += __shfl_xor(n2, m, 64);
            }
            if (lane == 0)
                score_out[node0 + wv * 4 + j] =
                    dot / (fmaxf(sqrtf(n2), 1e-8f) * pnorm);
        }
    }
}

// ---------------------------------------------------------------------------
// Fallback path (atomic scatter) if ws too small for CSR arrays.
__global__ void init_embeds_kernel(const int* __restrict__ nodes,
                                   const float* __restrict__ features,
                                   const float* __restrict__ node_emb,
                                   const float* __restrict__ feat_W,
                                   const float* __restrict__ feat_b,
                                   float* __restrict__ embeds) {
    int tid = blockIdx.x * blockDim.x + threadIdx.x;
    if (tid >= N_NODES * D) return;
    int node = tid >> 6;
    int d = tid & 63;
    float acc = feat_b[d];
    const float* f = features + (size_t)node * 10;
    const float* w = feat_W + (size_t)d * 10;
#pragma unroll
    for (int j = 0; j < 10; ++j) acc += f[j] * w[j];
    embeds[tid] = node_emb[(size_t)nodes[node] * D + d] + acc;
}

__global__ void scatter_add_kernel(const int* __restrict__ edges,
                                   const float* __restrict__ embeds,
                                   float* __restrict__ agg) {
    int tid = blockIdx.x * blockDim.x + threadIdx.x;
    int edge = tid >> 6;
    int lane = tid & 63;
    if (edge >= N_EDGES) return;
    int src = edges[2 * edge + 0];
    int dst = edges[2 * edge + 1];
    atomicAdd(&agg[(size_t)dst * D + lane], embeds[(size_t)src * D + lane]);
}

__global__ void conv_inplace_kernel(const float* __restrict__ agg,
                                    const float* __restrict__ W,
                                    const float* __restrict__ b,
                                    float* __restrict__ embeds) {
    __shared__ float Ws[D * 65];
    __shared__ float xs[4][D];
    for (int i = threadIdx.x; i < D * D; i += blockDim.x) {
        int d = i >> 6, k = i & 63;
        Ws[d * 65 + k] = W[i];
    }
    __syncthreads();
    int lane_d = threadIdx.x & 63;
    int local_n = threadIdx.x >> 6;
    float bias = b[lane_d];
    const int n_chunks = (N_NODES + 3) / 4;
    for (int chunk = blockIdx.x; chunk < n_chunks; chunk += gridDim.x) {
        int node = chunk * 4 + local_n;
        if (node < N_NODES) {
            size_t base = (size_t)node * D + lane_d;
            xs[local_n][lane_d] = embeds[base] + agg[base];
        }
        __syncthreads();
        if (node < N_NODES) {
            float acc = bias;
#pragma unroll
            for (int k = 0; k < D; ++k) acc += xs[local_n][k] * Ws[lane_d * 65 + k];
            embeds[(size_t)node * D + lane_d] = fmaxf(acc, 0.0f);
        }
        __syncthreads();
    }
}

__global__ void final_score_kernel(const float* __restrict__ embeds,
                                   const float* __restrict__ pattern_emb,
                                   const int* __restrict__ pattern_id,
                                   float* __restrict__ out) {
    int lane = threadIdx.x & 63;
    int wave = threadIdx.x >> 6;
    int node = blockIdx.x * 4 + wave;
    int pid = pattern_id[0];
    float p = pattern_emb[(size_t)pid * D + lane];
    float pn = p * p;
#pragma unroll
    for (int m = 32; m > 0; m >>= 1) pn += __shfl_xor(pn, m, 64);
    if (node < N_NODES) {
        float e = embeds[(size_t)node * D + lane];
        float dot = e * p;
        float n2 = e * e;
#pragma unroll
        for (int m = 32; m > 0; m >>= 1) {
            dot += __shfl_xor(dot, m, 64);
            n2  += __shfl_xor(n2, m, 64);
        }
        if (lane == 0) {
            float denom = fmaxf(sqrtf(n2), 1e-8f) * fmaxf(sqrtf(pn), 1e-8f);
            out[node] = dot / denom;
        }
    }
}

// ---------------------------------------------------------------------------
extern "C" void kernel_launch(void* const* d_in, const int* in_sizes, int n_in,
                              void* d_out, int out_size, void* d_ws, size_t ws_size,
                              hipStream_t stream) {
    const int*   nodes       = (const int*)d_in[0];
    const int*   edges       = (const int*)d_in[1];
    const float* features    = (const float*)d_in[2];
    const float* node_emb    = (const float*)d_in[3];
    const float* feat_W      = (const float*)d_in[4];
    const float* feat_b      = (const float*)d_in[5];
    const float* conv1_W     = (const float*)d_in[6];
    const float* conv1_b     = (const float*)d_in[7];
    const float* pattern_emb = (const float*)d_in[8];
    const int*   pattern_id  = (const int*)d_in[9];
    float* out = (float*)d_out;

    const size_t emb_bytes = (size_t)N_NODES * D * sizeof(float);       // 25.6 MB
    auto align256 = [](size_t x) { return (x + 255) & ~(size_t)255; };

    size_t o_embA = 0;
    size_t o_embB = o_embA + align256(emb_bytes);
    size_t o_col  = o_embB + align256(emb_bytes);
    size_t o_rank = o_col  + align256((size_t)N_EDGES * 4);
    size_t o_row  = o_rank + align256((size_t)N_EDGES * 4);
    size_t o_deg  = o_row  + align256((size_t)(N_NODES + 1) * 4);
    size_t o_bsum = o_deg  + align256((size_t)N_NODES * 4);
    size_t o_boff = o_bsum + align256((size_t)NB1 * 4);
    size_t need   = o_boff + align256((size_t)NB1 * 4);

    char* ws = (char*)d_ws;

    if (ws_size >= need) {
        float* embA = (float*)(ws + o_embA);
        float* embB = (float*)(ws + o_embB);
        int*   col  = (int*)(ws + o_col);
        int*   rank = (int*)(ws + o_rank);
        int*   rowp = (int*)(ws + o_row);
        int*   deg  = (int*)(ws + o_deg);
        int*   bsum = (int*)(ws + o_bsum);
        int*   boff = (int*)(ws + o_boff);

        hipMemsetAsync(deg, 0, (size_t)N_NODES * 4, stream);
        hist_rank_kernel<<<FILL_BLOCKS, 256, 0, stream>>>((const int2*)edges, deg, rank);
        scan1_kernel<<<NB1, SCAN_B, 0, stream>>>(deg, rowp, bsum);
        scan2_kernel<<<1, 512, 0, stream>>>(bsum, boff);
        scan3_kernel<<<NB1, SCAN_B, 0, stream>>>(rowp, boff);
        fill_init_kernel<<<FILL_BLOCKS + INIT_BLOCKS, 256, 0, stream>>>(
            (const int2*)edges, rank, rowp, col,
            nodes, features, node_emb, feat_W, feat_b, embA);

        fused_gather_conv_kernel<false><<<N_NODES / 16, 256, 0, stream>>>(
            embA, rowp, col, conv1_W, conv1_b, pattern_emb, pattern_id, embB, nullptr);
        fused_gather_conv_kernel<true><<<N_NODES / 16, 256, 0, stream>>>(
            embB, rowp, col, conv1_W, conv1_b, pattern_emb, pattern_id, nullptr, out);
    } else {
        float* embeds = (float*)ws;
        float* agg = (float*)(ws + align256(emb_bytes));
        init_embeds_kernel<<<(N_NODES * D + 255) / 256, 256, 0, stream>>>(
            nodes, features, node_emb, feat_W, feat_b, embeds);
        for (int it = 0; it < 2; ++it) {
            hipMemsetAsync(agg, 0, emb_bytes, stream);
            long long total = (long long)N_EDGES * 64;
            scatter_add_kernel<<<(int)((total + 255) / 256), 256, 0, stream>>>(edges, embeds, agg);
            conv_inplace_kernel<<<2048, 256, 0, stream>>>(agg, conv1_W, conv1_b, embeds);
        }
        final_score_kernel<<<(N_NODES + 3) / 4, 256, 0, stream>>>(
            embeds, pattern_emb, pattern_id, out);
    }
}

// Round 5
// 313.780 us; speedup vs baseline: 1.3892x; 1.3892x over previous
//
#include <hip/hip_runtime.h>
#include <hip/hip_bf16.h>

#define N_NODES 100000
#define N_EDGES 800000
#define D 64
#define SCAN_B 256
#define NB1 ((N_NODES + SCAN_B - 1) / SCAN_B)   // 391 blocks
#define FILL_BLOCKS (N_EDGES / 256)             // 3125, exact
#define INIT_BLOCKS (N_NODES * D / 256)         // 25000, exact

// ---------------------------------------------------------------------------
// hist + rank: deg[dst]++, rank[e] = arrival order of edge e at its dst.
__global__ __launch_bounds__(256) void hist_rank_kernel(
        const int2* __restrict__ edges,
        int* __restrict__ deg,
        int* __restrict__ rank) {
    int t = blockIdx.x * 256 + threadIdx.x;
    int2 e = edges[t];                      // grid exact: 3125*256 == N_EDGES
    rank[t] = atomicAdd(&deg[e.y], 1);
}

// ---------------------------------------------------------------------------
// Scans (exclusive prefix over deg -> row_ptr)
__global__ void scan1_kernel(const int* __restrict__ deg,
                             int* __restrict__ row_ptr,
                             int* __restrict__ bsum) {
    __shared__ int tmp[SCAN_B];
    int t = threadIdx.x;
    int i = blockIdx.x * SCAN_B + t;
    int v = (i < N_NODES) ? deg[i] : 0;
    tmp[t] = v;
    __syncthreads();
#pragma unroll
    for (int off = 1; off < SCAN_B; off <<= 1) {
        int a = (t >= off) ? tmp[t - off] : 0;
        __syncthreads();
        tmp[t] += a;
        __syncthreads();
    }
    if (i < N_NODES) row_ptr[i] = tmp[t] - v;   // exclusive
    if (t == SCAN_B - 1) bsum[blockIdx.x] = tmp[t];
}

__global__ void scan2_kernel(const int* __restrict__ bsum, int* __restrict__ boff) {
    __shared__ int tmp[512];
    int t = threadIdx.x;
    int v = (t < NB1) ? bsum[t] : 0;
    tmp[t] = v;
    __syncthreads();
#pragma unroll
    for (int off = 1; off < 512; off <<= 1) {
        int a = (t >= off) ? tmp[t - off] : 0;
        __syncthreads();
        tmp[t] += a;
        __syncthreads();
    }
    if (t < NB1) boff[t] = tmp[t] - v;
}

__global__ void scan3_kernel(int* __restrict__ row_ptr,
                             const int* __restrict__ boff) {
    int i = blockIdx.x * SCAN_B + threadIdx.x;
    if (i < N_NODES) row_ptr[i] += boff[i >> 8];
    if (i == 0) row_ptr[N_NODES] = N_EDGES;
}

// ---------------------------------------------------------------------------
// Fused dispatch: blocks [0, FILL_BLOCKS) scatter CSR cols (atomic-free via
// rank); blocks [FILL_BLOCKS, +INIT_BLOCKS) compute initial embeddings.
__global__ __launch_bounds__(256) void fill_init_kernel(
        const int2* __restrict__ edges,
        const int* __restrict__ rank,
        const int* __restrict__ rowp,
        int* __restrict__ col,
        const int* __restrict__ nodes,
        const float* __restrict__ features,
        const float* __restrict__ node_emb,
        const float* __restrict__ feat_W,
        const float* __restrict__ feat_b,
        float* __restrict__ embeds) {
    if (blockIdx.x < FILL_BLOCKS) {
        int t = blockIdx.x * 256 + threadIdx.x;
        int2 e = edges[t];
        col[rowp[e.y] + rank[t]] = e.x;
    } else {
        int tid = (blockIdx.x - FILL_BLOCKS) * 256 + threadIdx.x;
        int node = tid >> 6;
        int d = tid & 63;
        float acc = feat_b[d];
        const float* f = features + (size_t)node * 10;
        const float* w = feat_W + (size_t)d * 10;
#pragma unroll
        for (int j = 0; j < 10; ++j) acc += f[j] * w[j];
        embeds[tid] = node_emb[(size_t)nodes[node] * D + d] + acc;
    }
}

// ---------------------------------------------------------------------------
// x[node] = emb_in[node] + sum_{src in N(node)} emb_in[src]
// One WAVE per node (wave-uniform trip counts -> no divergence).
// 4 groups x 16 lanes: group g loads row of src (r*4+g), lane c = float4 chunk.
// 32-edge chunks, inner statically unrolled 8 rounds with per-lane predication:
// 8 independent float4 loads in flight; 4 accumulators break the add chain.
__global__ __launch_bounds__(256, 6) void gather_x_kernel(
        const float* __restrict__ emb_in,
        const int* __restrict__ rowp,
        const int* __restrict__ col,
        float* __restrict__ x_out) {
    int lane = threadIdx.x & 63;
    int wv   = threadIdx.x >> 6;
    int node = blockIdx.x * 4 + wv;          // grid = 25000, exact
    int g = lane >> 4;                        // row-group 0..3
    int c = lane & 15;                        // float4 chunk 0..15

    int start = rowp[node];
    int end   = rowp[node + 1];

    float4 acc[4];
#pragma unroll
    for (int r = 0; r < 4; ++r) acc[r] = make_float4(0.f, 0.f, 0.f, 0.f);
    if (g == 0)                               // self term, counted once
        acc[0] = ((const float4*)(emb_in + (size_t)node * D))[c];

    for (int base = start; base < end; base += 32) {
        int nb = end - base; if (nb > 32) nb = 32;
        int idx = (lane < nb) ? col[base + lane] : 0;   // lanes 0..31, coalesced
#pragma unroll
        for (int r = 0; r < 8; ++r) {
            int s = r * 4 + g;                          // 0..31
            int src = __shfl(idx, s, 64);               // all lanes active
            if (s < nb) {                               // per-lane predication
                float4 v = ((const float4*)(emb_in + (size_t)src * D))[c];
                acc[r & 3].x += v.x; acc[r & 3].y += v.y;
                acc[r & 3].z += v.z; acc[r & 3].w += v.w;
            }
        }
    }

    float4 a;
    a.x = (acc[0].x + acc[1].x) + (acc[2].x + acc[3].x);
    a.y = (acc[0].y + acc[1].y) + (acc[2].y + acc[3].y);
    a.z = (acc[0].z + acc[1].z) + (acc[2].z + acc[3].z);
    a.w = (acc[0].w + acc[1].w) + (acc[2].w + acc[3].w);

    // combine the 4 group partials (xor 16, 32)
    a.x += __shfl_xor(a.x, 16, 64); a.y += __shfl_xor(a.y, 16, 64);
    a.z += __shfl_xor(a.z, 16, 64); a.w += __shfl_xor(a.w, 16, 64);
    a.x += __shfl_xor(a.x, 32, 64); a.y += __shfl_xor(a.y, 32, 64);
    a.z += __shfl_xor(a.z, 32, 64); a.w += __shfl_xor(a.w, 32, 64);

    if (g == 0)                               // 16 lanes x 16 B = full 256 B row
        ((float4*)(x_out + (size_t)node * D))[c] = a;
}

// ---------------------------------------------------------------------------
// emb_out = relu(x @ W^T + b); if SCORE, emit cosine-vs-pattern instead.
// Grid-stride over 4-node chunks; wave wv owns node chunk*4+wv; lane = out dim.
// W row in VGPRs, amortized over ~12 chunks per block.
template <bool SCORE>
__global__ __launch_bounds__(256) void conv_kernel(
        const float* __restrict__ x,
        const float* __restrict__ W,
        const float* __restrict__ b,
        const float* __restrict__ pattern_emb,
        const int* __restrict__ pattern_id,
        float* __restrict__ emb_out,
        float* __restrict__ score_out) {
    __shared__ float4 xs[4][16];

    int lane = threadIdx.x & 63;
    int wv   = threadIdx.x >> 6;
    float bias = b[lane];

    float4 Wr[16];
    const float4* W4 = (const float4*)(W + (size_t)lane * D);
#pragma unroll
    for (int k = 0; k < 16; ++k) Wr[k] = W4[k];

    float p = 0.f, pnorm = 1.f;
    if (SCORE) {
        p = pattern_emb[(size_t)pattern_id[0] * D + lane];
        float pn = p * p;
#pragma unroll
        for (int m = 32; m > 0; m >>= 1) pn += __shfl_xor(pn, m, 64);
        pnorm = fmaxf(sqrtf(pn), 1e-8f);
    }

    const int n_chunks = N_NODES / 4;         // 25000, exact
    for (int chunk = blockIdx.x; chunk < n_chunks; chunk += gridDim.x) {
        int node = chunk * 4 + wv;
        if (lane < 16)
            xs[wv][lane] = ((const float4*)(x + (size_t)node * D))[lane];
        // intra-wave producer->consumer through LDS: drain loads, order ds ops
        asm volatile("s_waitcnt vmcnt(0) lgkmcnt(0)" ::: "memory");
        float y = bias;
#pragma unroll
        for (int k = 0; k < 16; ++k) {
            float4 x4 = xs[wv][k];            // wave-broadcast ds_read_b128
            y += Wr[k].x * x4.x + Wr[k].y * x4.y + Wr[k].z * x4.z + Wr[k].w * x4.w;
        }
        y = fmaxf(y, 0.0f);
        if (!SCORE) {
            emb_out[(size_t)node * D + lane] = y;
        } else {
            float dot = y * p;
            float n2  = y * y;
#pragma unroll
            for (int m = 32; m > 0; m >>= 1) {
                dot += __shfl_xor(dot, m, 64);
                n2  += __shfl_xor(n2, m, 64);
            }
            if (lane == 0)
                score_out[node] = dot / (fmaxf(sqrtf(n2), 1e-8f) * pnorm);
        }
    }
}

// ---------------------------------------------------------------------------
// Fallback path (atomic scatter) if ws too small for CSR arrays.
__global__ void init_embeds_kernel(const int* __restrict__ nodes,
                                   const float* __restrict__ features,
                                   const float* __restrict__ node_emb,
                                   const float* __restrict__ feat_W,
                                   const float* __restrict__ feat_b,
                                   float* __restrict__ embeds) {
    int tid = blockIdx.x * blockDim.x + threadIdx.x;
    if (tid >= N_NODES * D) return;
    int node = tid >> 6;
    int d = tid & 63;
    float acc = feat_b[d];
    const float* f = features + (size_t)node * 10;
    const float* w = feat_W + (size_t)d * 10;
#pragma unroll
    for (int j = 0; j < 10; ++j) acc += f[j] * w[j];
    embeds[tid] = node_emb[(size_t)nodes[node] * D + d] + acc;
}

__global__ void scatter_add_kernel(const int* __restrict__ edges,
                                   const float* __restrict__ embeds,
                                   float* __restrict__ agg) {
    int tid = blockIdx.x * blockDim.x + threadIdx.x;
    int edge = tid >> 6;
    int lane = tid & 63;
    if (edge >= N_EDGES) return;
    int src = edges[2 * edge + 0];
    int dst = edges[2 * edge + 1];
    atomicAdd(&agg[(size_t)dst * D + lane], embeds[(size_t)src * D + lane]);
}

__global__ void conv_inplace_kernel(const float* __restrict__ agg,
                                    const float* __restrict__ W,
                                    const float* __restrict__ b,
                                    float* __restrict__ embeds) {
    __shared__ float Ws[D * 65];
    __shared__ float xs[4][D];
    for (int i = threadIdx.x; i < D * D; i += blockDim.x) {
        int d = i >> 6, k = i & 63;
        Ws[d * 65 + k] = W[i];
    }
    __syncthreads();
    int lane_d = threadIdx.x & 63;
    int local_n = threadIdx.x >> 6;
    float bias = b[lane_d];
    const int n_chunks = (N_NODES + 3) / 4;
    for (int chunk = blockIdx.x; chunk < n_chunks; chunk += gridDim.x) {
        int node = chunk * 4 + local_n;
        if (node < N_NODES) {
            size_t base = (size_t)node * D + lane_d;
            xs[local_n][lane_d] = embeds[base] + agg[base];
        }
        __syncthreads();
        if (node < N_NODES) {
            float acc = bias;
#pragma unroll
            for (int k = 0; k < D; ++k) acc += xs[local_n][k] * Ws[lane_d * 65 + k];
            embeds[(size_t)node * D + lane_d] = fmaxf(acc, 0.0f);
        }
        __syncthreads();
    }
}

__global__ void final_score_kernel(const float* __restrict__ embeds,
                                   const float* __restrict__ pattern_emb,
                                   const int* __restrict__ pattern_id,
                                   float* __restrict__ out) {
    int lane = threadIdx.x & 63;
    int wave = threadIdx.x >> 6;
    int node = blockIdx.x * 4 + wave;
    int pid = pattern_id[0];
    float p = pattern_emb[(size_t)pid * D + lane];
    float pn = p * p;
#pragma unroll
    for (int m = 32; m > 0; m >>= 1) pn += __shfl_xor(pn, m, 64);
    if (node < N_NODES) {
        float e = embeds[(size_t)node * D + lane];
        float dot = e * p;
        float n2 = e * e;
#pragma unroll
        for (int m = 32; m > 0; m >>= 1) {
            dot += __shfl_xor(dot, m, 64);
            n2  += __shfl_xor(n2, m, 64);
        }
        if (lane == 0) {
            float denom = fmaxf(sqrtf(n2), 1e-8f) * fmaxf(sqrtf(pn), 1e-8f);
            out[node] = dot / denom;
        }
    }
}

// ---------------------------------------------------------------------------
extern "C" void kernel_launch(void* const* d_in, const int* in_sizes, int n_in,
                              void* d_out, int out_size, void* d_ws, size_t ws_size,
                              hipStream_t stream) {
    const int*   nodes       = (const int*)d_in[0];
    const int*   edges       = (const int*)d_in[1];
    const float* features    = (const float*)d_in[2];
    const float* node_emb    = (const float*)d_in[3];
    const float* feat_W      = (const float*)d_in[4];
    const float* feat_b      = (const float*)d_in[5];
    const float* conv1_W     = (const float*)d_in[6];
    const float* conv1_b     = (const float*)d_in[7];
    const float* pattern_emb = (const float*)d_in[8];
    const int*   pattern_id  = (const int*)d_in[9];
    float* out = (float*)d_out;

    const size_t emb_bytes = (size_t)N_NODES * D * sizeof(float);       // 25.6 MB
    auto align256 = [](size_t x) { return (x + 255) & ~(size_t)255; };

    size_t o_embA = 0;
    size_t o_embB = o_embA + align256(emb_bytes);
    size_t o_xbuf = o_embB + align256(emb_bytes);
    size_t o_col  = o_xbuf + align256(emb_bytes);
    size_t o_rank = o_col  + align256((size_t)N_EDGES * 4);
    size_t o_row  = o_rank + align256((size_t)N_EDGES * 4);
    size_t o_deg  = o_row  + align256((size_t)(N_NODES + 1) * 4);
    size_t o_bsum = o_deg  + align256((size_t)N_NODES * 4);
    size_t o_boff = o_bsum + align256((size_t)NB1 * 4);
    size_t need   = o_boff + align256((size_t)NB1 * 4);

    char* ws = (char*)d_ws;

    if (ws_size >= need) {
        float* embA = (float*)(ws + o_embA);
        float* embB = (float*)(ws + o_embB);
        float* xbuf = (float*)(ws + o_xbuf);
        int*   col  = (int*)(ws + o_col);
        int*   rank = (int*)(ws + o_rank);
        int*   rowp = (int*)(ws + o_row);
        int*   deg  = (int*)(ws + o_deg);
        int*   bsum = (int*)(ws + o_bsum);
        int*   boff = (int*)(ws + o_boff);

        hipMemsetAsync(deg, 0, (size_t)N_NODES * 4, stream);
        hist_rank_kernel<<<FILL_BLOCKS, 256, 0, stream>>>((const int2*)edges, deg, rank);
        scan1_kernel<<<NB1, SCAN_B, 0, stream>>>(deg, rowp, bsum);
        scan2_kernel<<<1, 512, 0, stream>>>(bsum, boff);
        scan3_kernel<<<NB1, SCAN_B, 0, stream>>>(rowp, boff);
        fill_init_kernel<<<FILL_BLOCKS + INIT_BLOCKS, 256, 0, stream>>>(
            (const int2*)edges, rank, rowp, col,
            nodes, features, node_emb, feat_W, feat_b, embA);

        // iter 1: gather + conv -> embB
        gather_x_kernel<<<N_NODES / 4, 256, 0, stream>>>(embA, rowp, col, xbuf);
        conv_kernel<false><<<2048, 256, 0, stream>>>(
            xbuf, conv1_W, conv1_b, pattern_emb, pattern_id, embB, nullptr);
        // iter 2: gather + conv fused with cosine score -> out
        gather_x_kernel<<<N_NODES / 4, 256, 0, stream>>>(embB, rowp, col, xbuf);
        conv_kernel<true><<<2048, 256, 0, stream>>>(
            xbuf, conv1_W, conv1_b, pattern_emb, pattern_id, nullptr, out);
    } else {
        float* embeds = (float*)ws;
        float* agg = (float*)(ws + align256(emb_bytes));
        init_embeds_kernel<<<(N_NODES * D + 255) / 256, 256, 0, stream>>>(
            nodes, features, node_emb, feat_W, feat_b, embeds);
        for (int it = 0; it < 2; ++it) {
            hipMemsetAsync(agg, 0, emb_bytes, stream);
            long long total = (long long)N_EDGES * 64;
            scatter_add_kernel<<<(int)((total + 255) / 256), 256, 0, stream>>>(edges, embeds, agg);
            conv_inplace_kernel<<<2048, 256, 0, stream>>>(agg, conv1_W, conv1_b, embeds);
        }
        final_score_kernel<<<(N_NODES + 3) / 4, 256, 0, stream>>>(
            embeds, pattern_emb, pattern_id, out);
    }
}

// Round 6
// 300.571 us; speedup vs baseline: 1.4503x; 1.0439x over previous
//
#include <hip/hip_runtime.h>
#include <hip/hip_bf16.h>

#define N_NODES 100000
#define N_EDGES 800000
#define D 64
#define SCAN_B 256
#define NB1 ((N_NODES + SCAN_B - 1) / SCAN_B)   // 391 blocks
#define FILL_BLOCKS (N_EDGES / 256)             // 3125, exact
#define INIT_BLOCKS (N_NODES * D / 256)         // 25000, exact

// bf16 helpers: storage-only bf16 (embeds); all math in fp32.
__device__ __forceinline__ unsigned short f2bf(float f) {
    union { float f; unsigned u; } v; v.f = f;
    unsigned r = v.u + 0x7fffu + ((v.u >> 16) & 1u);   // round-to-nearest-even
    return (unsigned short)(r >> 16);
}
__device__ __forceinline__ void acc_bf8(float acc[8], uint4 u) {
    acc[0] += __uint_as_float(u.x << 16);
    acc[1] += __uint_as_float(u.x & 0xffff0000u);
    acc[2] += __uint_as_float(u.y << 16);
    acc[3] += __uint_as_float(u.y & 0xffff0000u);
    acc[4] += __uint_as_float(u.z << 16);
    acc[5] += __uint_as_float(u.z & 0xffff0000u);
    acc[6] += __uint_as_float(u.w << 16);
    acc[7] += __uint_as_float(u.w & 0xffff0000u);
}

// ---------------------------------------------------------------------------
// hist + rank: deg[dst]++, rank[e] = arrival order of edge e at its dst.
__global__ __launch_bounds__(256) void hist_rank_kernel(
        const int2* __restrict__ edges,
        int* __restrict__ deg,
        int* __restrict__ rank) {
    int t = blockIdx.x * 256 + threadIdx.x;
    int2 e = edges[t];                      // grid exact: 3125*256 == N_EDGES
    rank[t] = atomicAdd(&deg[e.y], 1);
}

// ---------------------------------------------------------------------------
// Scans (exclusive prefix over deg -> row_ptr)
__global__ void scan1_kernel(const int* __restrict__ deg,
                             int* __restrict__ row_ptr,
                             int* __restrict__ bsum) {
    __shared__ int tmp[SCAN_B];
    int t = threadIdx.x;
    int i = blockIdx.x * SCAN_B + t;
    int v = (i < N_NODES) ? deg[i] : 0;
    tmp[t] = v;
    __syncthreads();
#pragma unroll
    for (int off = 1; off < SCAN_B; off <<= 1) {
        int a = (t >= off) ? tmp[t - off] : 0;
        __syncthreads();
        tmp[t] += a;
        __syncthreads();
    }
    if (i < N_NODES) row_ptr[i] = tmp[t] - v;   // exclusive
    if (t == SCAN_B - 1) bsum[blockIdx.x] = tmp[t];
}

__global__ void scan2_kernel(const int* __restrict__ bsum, int* __restrict__ boff) {
    __shared__ int tmp[512];
    int t = threadIdx.x;
    int v = (t < NB1) ? bsum[t] : 0;
    tmp[t] = v;
    __syncthreads();
#pragma unroll
    for (int off = 1; off < 512; off <<= 1) {
        int a = (t >= off) ? tmp[t - off] : 0;
        __syncthreads();
        tmp[t] += a;
        __syncthreads();
    }
    if (t < NB1) boff[t] = tmp[t] - v;
}

__global__ void scan3_kernel(int* __restrict__ row_ptr,
                             const int* __restrict__ boff) {
    int i = blockIdx.x * SCAN_B + threadIdx.x;
    if (i < N_NODES) row_ptr[i] += boff[i >> 8];
    if (i == 0) row_ptr[N_NODES] = N_EDGES;
}

// ---------------------------------------------------------------------------
// Fused dispatch: blocks [0, FILL_BLOCKS) scatter CSR cols (atomic-free via
// rank); blocks [FILL_BLOCKS, +INIT_BLOCKS) compute initial embeddings (bf16).
__global__ __launch_bounds__(256) void fill_init_kernel(
        const int2* __restrict__ edges,
        const int* __restrict__ rank,
        const int* __restrict__ rowp,
        int* __restrict__ col,
        const int* __restrict__ nodes,
        const float* __restrict__ features,
        const float* __restrict__ node_emb,
        const float* __restrict__ feat_W,
        const float* __restrict__ feat_b,
        unsigned short* __restrict__ embeds) {
    if (blockIdx.x < FILL_BLOCKS) {
        int t = blockIdx.x * 256 + threadIdx.x;
        int2 e = edges[t];
        col[rowp[e.y] + rank[t]] = e.x;
    } else {
        int tid = (blockIdx.x - FILL_BLOCKS) * 256 + threadIdx.x;
        int node = tid >> 6;
        int d = tid & 63;
        float acc = feat_b[d];
        const float* f = features + (size_t)node * 10;
        const float* w = feat_W + (size_t)d * 10;
#pragma unroll
        for (int j = 0; j < 10; ++j) acc += f[j] * w[j];
        embeds[tid] = f2bf(node_emb[(size_t)nodes[node] * D + d] + acc);
    }
}

// ---------------------------------------------------------------------------
// x[node] = emb_in[node] + sum_{src} emb_in[src]   (emb bf16, acc fp32)
// One WAVE per node (uniform trips). 8 groups x 8 lanes: group g loads the
// row of src (r*8+g) as uint4 (8 bf16 = 16 B/lane, 128 B/row coalesced).
// 32-edge chunks, 4 static rounds: 8 independent rows in flight per wave.
__global__ __launch_bounds__(256, 6) void gather_x_kernel(
        const unsigned short* __restrict__ emb_in,
        const int* __restrict__ rowp,
        const int* __restrict__ col,
        float* __restrict__ x_out) {
    int lane = threadIdx.x & 63;
    int wv   = threadIdx.x >> 6;
    int node = blockIdx.x * 4 + wv;          // grid = 25000, exact
    int g = lane >> 3;                        // row-group 0..7
    int c = lane & 7;                         // uint4 chunk 0..7

    int start = rowp[node];
    int end   = rowp[node + 1];

    float acc[8];
#pragma unroll
    for (int j = 0; j < 8; ++j) acc[j] = 0.f;
    if (g == 0) {                             // self term, counted once
        uint4 u = ((const uint4*)(emb_in + (size_t)node * D))[c];
        acc_bf8(acc, u);
    }

    for (int base = start; base < end; base += 32) {
        int nb = end - base; if (nb > 32) nb = 32;
        int idx = (lane < nb) ? col[base + lane] : 0;   // lanes 0..31, coalesced
#pragma unroll
        for (int r = 0; r < 4; ++r) {
            int s = r * 8 + g;                          // 0..31
            int src = __shfl(idx, s, 64);               // all lanes active
            if (s < nb) {                               // per-lane predication
                uint4 u = ((const uint4*)(emb_in + (size_t)src * D))[c];
                acc_bf8(acc, u);
            }
        }
    }

    // combine the 8 group partials (xor 8, 16, 32)
#pragma unroll
    for (int m = 8; m <= 32; m <<= 1) {
#pragma unroll
        for (int j = 0; j < 8; ++j) acc[j] += __shfl_xor(acc[j], m, 64);
    }

    if (g == 0) {                             // 8 lanes x 32 B = 256 B fp32 row
        float4 a0 = make_float4(acc[0], acc[1], acc[2], acc[3]);
        float4 a1 = make_float4(acc[4], acc[5], acc[6], acc[7]);
        float4* o = (float4*)(x_out + (size_t)node * D);
        o[2 * c]     = a0;
        o[2 * c + 1] = a1;
    }
}

// ---------------------------------------------------------------------------
// y = relu(x @ W^T + b); !SCORE: store bf16 embeds; SCORE: cosine-vs-pattern.
// Grid-stride over 4-node chunks; wave wv owns node chunk*4+wv; lane = out dim.
template <bool SCORE>
__global__ __launch_bounds__(256) void conv_kernel(
        const float* __restrict__ x,
        const float* __restrict__ W,
        const float* __restrict__ b,
        const float* __restrict__ pattern_emb,
        const int* __restrict__ pattern_id,
        unsigned short* __restrict__ emb_out,
        float* __restrict__ score_out) {
    __shared__ float4 xs[4][16];

    int lane = threadIdx.x & 63;
    int wv   = threadIdx.x >> 6;
    float bias = b[lane];

    float4 Wr[16];
    const float4* W4 = (const float4*)(W + (size_t)lane * D);
#pragma unroll
    for (int k = 0; k < 16; ++k) Wr[k] = W4[k];

    float p = 0.f, pnorm = 1.f;
    if (SCORE) {
        p = pattern_emb[(size_t)pattern_id[0] * D + lane];
        float pn = p * p;
#pragma unroll
        for (int m = 32; m > 0; m >>= 1) pn += __shfl_xor(pn, m, 64);
        pnorm = fmaxf(sqrtf(pn), 1e-8f);
    }

    const int n_chunks = N_NODES / 4;         // 25000, exact
    for (int chunk = blockIdx.x; chunk < n_chunks; chunk += gridDim.x) {
        int node = chunk * 4 + wv;
        if (lane < 16)
            xs[wv][lane] = ((const float4*)(x + (size_t)node * D))[lane];
        // intra-wave producer->consumer through LDS: drain loads, order ds ops
        asm volatile("s_waitcnt vmcnt(0) lgkmcnt(0)" ::: "memory");
        float y = bias;
#pragma unroll
        for (int k = 0; k < 16; ++k) {
            float4 x4 = xs[wv][k];            // wave-broadcast ds_read_b128
            y += Wr[k].x * x4.x + Wr[k].y * x4.y + Wr[k].z * x4.z + Wr[k].w * x4.w;
        }
        y = fmaxf(y, 0.0f);
        if (!SCORE) {
            emb_out[(size_t)node * D + lane] = f2bf(y);
        } else {
            float dot = y * p;
            float n2  = y * y;
#pragma unroll
            for (int m = 32; m > 0; m >>= 1) {
                dot += __shfl_xor(dot, m, 64);
                n2  += __shfl_xor(n2, m, 64);
            }
            if (lane == 0)
                score_out[node] = dot / (fmaxf(sqrtf(n2), 1e-8f) * pnorm);
        }
    }
}

// ---------------------------------------------------------------------------
// Fallback path (atomic scatter, full fp32) if ws too small for CSR arrays.
__global__ void init_embeds_kernel(const int* __restrict__ nodes,
                                   const float* __restrict__ features,
                                   const float* __restrict__ node_emb,
                                   const float* __restrict__ feat_W,
                                   const float* __restrict__ feat_b,
                                   float* __restrict__ embeds) {
    int tid = blockIdx.x * blockDim.x + threadIdx.x;
    if (tid >= N_NODES * D) return;
    int node = tid >> 6;
    int d = tid & 63;
    float acc = feat_b[d];
    const float* f = features + (size_t)node * 10;
    const float* w = feat_W + (size_t)d * 10;
#pragma unroll
    for (int j = 0; j < 10; ++j) acc += f[j] * w[j];
    embeds[tid] = node_emb[(size_t)nodes[node] * D + d] + acc;
}

__global__ void scatter_add_kernel(const int* __restrict__ edges,
                                   const float* __restrict__ embeds,
                                   float* __restrict__ agg) {
    int tid = blockIdx.x * blockDim.x + threadIdx.x;
    int edge = tid >> 6;
    int lane = tid & 63;
    if (edge >= N_EDGES) return;
    int src = edges[2 * edge + 0];
    int dst = edges[2 * edge + 1];
    atomicAdd(&agg[(size_t)dst * D + lane], embeds[(size_t)src * D + lane]);
}

__global__ void conv_inplace_kernel(const float* __restrict__ agg,
                                    const float* __restrict__ W,
                                    const float* __restrict__ b,
                                    float* __restrict__ embeds) {
    __shared__ float Ws[D * 65];
    __shared__ float xs[4][D];
    for (int i = threadIdx.x; i < D * D; i += blockDim.x) {
        int d = i >> 6, k = i & 63;
        Ws[d * 65 + k] = W[i];
    }
    __syncthreads();
    int lane_d = threadIdx.x & 63;
    int local_n = threadIdx.x >> 6;
    float bias = b[lane_d];
    const int n_chunks = (N_NODES + 3) / 4;
    for (int chunk = blockIdx.x; chunk < n_chunks; chunk += gridDim.x) {
        int node = chunk * 4 + local_n;
        if (node < N_NODES) {
            size_t base = (size_t)node * D + lane_d;
            xs[local_n][lane_d] = embeds[base] + agg[base];
        }
        __syncthreads();
        if (node < N_NODES) {
            float acc = bias;
#pragma unroll
            for (int k = 0; k < D; ++k) acc += xs[local_n][k] * Ws[lane_d * 65 + k];
            embeds[(size_t)node * D + lane_d] = fmaxf(acc, 0.0f);
        }
        __syncthreads();
    }
}

__global__ void final_score_kernel(const float* __restrict__ embeds,
                                   const float* __restrict__ pattern_emb,
                                   const int* __restrict__ pattern_id,
                                   float* __restrict__ out) {
    int lane = threadIdx.x & 63;
    int wave = threadIdx.x >> 6;
    int node = blockIdx.x * 4 + wave;
    int pid = pattern_id[0];
    float p = pattern_emb[(size_t)pid * D + lane];
    float pn = p * p;
#pragma unroll
    for (int m = 32; m > 0; m >>= 1) pn += __shfl_xor(pn, m, 64);
    if (node < N_NODES) {
        float e = embeds[(size_t)node * D + lane];
        float dot = e * p;
        float n2 = e * e;
#pragma unroll
        for (int m = 32; m > 0; m >>= 1) {
            dot += __shfl_xor(dot, m, 64);
            n2  += __shfl_xor(n2, m, 64);
        }
        if (lane == 0) {
            float denom = fmaxf(sqrtf(n2), 1e-8f) * fmaxf(sqrtf(pn), 1e-8f);
            out[node] = dot / denom;
        }
    }
}

// ---------------------------------------------------------------------------
extern "C" void kernel_launch(void* const* d_in, const int* in_sizes, int n_in,
                              void* d_out, int out_size, void* d_ws, size_t ws_size,
                              hipStream_t stream) {
    const int*   nodes       = (const int*)d_in[0];
    const int*   edges       = (const int*)d_in[1];
    const float* features    = (const float*)d_in[2];
    const float* node_emb    = (const float*)d_in[3];
    const float* feat_W      = (const float*)d_in[4];
    const float* feat_b      = (const float*)d_in[5];
    const float* conv1_W     = (const float*)d_in[6];
    const float* conv1_b     = (const float*)d_in[7];
    const float* pattern_emb = (const float*)d_in[8];
    const int*   pattern_id  = (const int*)d_in[9];
    float* out = (float*)d_out;

    const size_t emb_f32_bytes = (size_t)N_NODES * D * sizeof(float);   // 25.6 MB
    const size_t emb_bf_bytes  = (size_t)N_NODES * D * 2;               // 12.8 MB
    auto align256 = [](size_t x) { return (x + 255) & ~(size_t)255; };

    size_t o_embA = 0;
    size_t o_embB = o_embA + align256(emb_bf_bytes);
    size_t o_xbuf = o_embB + align256(emb_bf_bytes);
    size_t o_col  = o_xbuf + align256(emb_f32_bytes);
    size_t o_rank = o_col  + align256((size_t)N_EDGES * 4);
    size_t o_row  = o_rank + align256((size_t)N_EDGES * 4);
    size_t o_deg  = o_row  + align256((size_t)(N_NODES + 1) * 4);
    size_t o_bsum = o_deg  + align256((size_t)N_NODES * 4);
    size_t o_boff = o_bsum + align256((size_t)NB1 * 4);
    size_t need   = o_boff + align256((size_t)NB1 * 4);

    char* ws = (char*)d_ws;

    if (ws_size >= need) {
        unsigned short* embA = (unsigned short*)(ws + o_embA);
        unsigned short* embB = (unsigned short*)(ws + o_embB);
        float* xbuf = (float*)(ws + o_xbuf);
        int*   col  = (int*)(ws + o_col);
        int*   rank = (int*)(ws + o_rank);
        int*   rowp = (int*)(ws + o_row);
        int*   deg  = (int*)(ws + o_deg);
        int*   bsum = (int*)(ws + o_bsum);
        int*   boff = (int*)(ws + o_boff);

        hipMemsetAsync(deg, 0, (size_t)N_NODES * 4, stream);
        hist_rank_kernel<<<FILL_BLOCKS, 256, 0, stream>>>((const int2*)edges, deg, rank);
        scan1_kernel<<<NB1, SCAN_B, 0, stream>>>(deg, rowp, bsum);
        scan2_kernel<<<1, 512, 0, stream>>>(bsum, boff);
        scan3_kernel<<<NB1, SCAN_B, 0, stream>>>(rowp, boff);
        fill_init_kernel<<<FILL_BLOCKS + INIT_BLOCKS, 256, 0, stream>>>(
            (const int2*)edges, rank, rowp, col,
            nodes, features, node_emb, feat_W, feat_b, embA);

        // iter 1: gather(bf16->fp32) + conv -> embB (bf16)
        gather_x_kernel<<<N_NODES / 4, 256, 0, stream>>>(embA, rowp, col, xbuf);
        conv_kernel<false><<<2048, 256, 0, stream>>>(
            xbuf, conv1_W, conv1_b, pattern_emb, pattern_id, embB, nullptr);
        // iter 2: gather + conv fused with cosine score -> out
        gather_x_kernel<<<N_NODES / 4, 256, 0, stream>>>(embB, rowp, col, xbuf);
        conv_kernel<true><<<2048, 256, 0, stream>>>(
            xbuf, conv1_W, conv1_b, pattern_emb, pattern_id, nullptr, out);
    } else {
        float* embeds = (float*)ws;
        float* agg = (float*)(ws + align256(emb_f32_bytes));
        init_embeds_kernel<<<(N_NODES * D + 255) / 256, 256, 0, stream>>>(
            nodes, features, node_emb, feat_W, feat_b, embeds);
        for (int it = 0; it < 2; ++it) {
            hipMemsetAsync(agg, 0, emb_f32_bytes, stream);
            long long total = (long long)N_EDGES * 64;
            scatter_add_kernel<<<(int)((total + 255) / 256), 256, 0, stream>>>(edges, embeds, agg);
            conv_inplace_kernel<<<2048, 256, 0, stream>>>(agg, conv1_W, conv1_b, embeds);
        }
        final_score_kernel<<<(N_NODES + 3) / 4, 256, 0, stream>>>(
            embeds, pattern_emb, pattern_id, out);
    }
}